// Round 7
// baseline (122.745 us; speedup 1.0000x reference)
//
#include <hip/hip_runtime.h>
#include <hip/hip_bf16.h>
#include <math.h>

#define KK 5
#define KN 32
#define CIN 16
#define H 64
#define W 64
#define NB 32
#define HO 60
#define WO 60
#define D_TOT 400
#define OUT_PLANE (NB*HO*WO*KN)

// block tile: 8 out-rows x 16 out-cols, 4 waves, each wave 2 rows.
// Each block does TWO tiles (same ho0/wo0, batches z and z+16), double-buffered:
// tile1's global loads are issued before tile0's k-loop so HBM read latency
// hides under compute + stores (attacks the phase-lock found in R2-R5).
#define TH 8
#define TW 16
#define IN_R 12      // TH + KK - 1
#define IN_C 20      // TW + KK - 1
#define CPAD 24      // c padded 16 -> 24 shorts (48B col stride: 2-way banks, free)
#define TILE_SH (IN_R*IN_C*CPAD)     // 5760 shorts per map
#define BUF_BYTES (2*TILE_SH*2)      // 23040 B per buffer (mu map + sigma map)
#define NKSTEP 13                    // ceil(400/32)
#define NLOAD (IN_R*IN_C*4)          // 960 float4-pairs per tile

typedef short short8 __attribute__((ext_vector_type(8)));
typedef float f32x4 __attribute__((ext_vector_type(4)));

__device__ __forceinline__ ushort f2bf(float x) {
    __hip_bfloat16 h = __float2bfloat16(x);
    return *reinterpret_cast<ushort*>(&h);
}
__device__ __forceinline__ float bf2f(ushort u) {
    __hip_bfloat16 h = *reinterpret_cast<__hip_bfloat16*>(&u);
    return __bfloat162float(h);
}
__device__ __forceinline__ ushort4 pk4(float4 v) {
    union { __hip_bfloat162 h; ushort2 u; } a, b;
    a.h = __float22bfloat162_rn(make_float2(v.x, v.y));
    b.h = __float22bfloat162_rn(make_float2(v.z, v.w));
    ushort4 r;
    r.x = a.u.x; r.y = a.u.y; r.z = b.u.x; r.w = b.u.y;
    return r;
}
__device__ __forceinline__ float softplusf(float x) {
    return (x > 20.0f) ? x : __logf(1.0f + __expf(x));
}

// ---------------- prep: pack B fragments + spw + KL (unchanged from R4) ----
__global__ void prep_all(const float* __restrict__ w_mu, const float* __restrict__ w_sigma,
                         ushort* __restrict__ bmu, ushort* __restrict__ bsq,
                         float* __restrict__ spw, float* __restrict__ kl_out) {
    __shared__ float red[256];
    int t = threadIdx.x;
    if (blockIdx.x < 52) {
        int idx = blockIdx.x * 256 + t;     // < 13312
        int j  = idx & 7;
        int l  = (idx >> 3) & 63;
        int nt = (idx >> 9) & 1;
        int ts = idx >> 10;
        int k  = ts * 32 + ((l >> 4) & 3) * 8 + j;
        int n  = nt * 16 + (l & 15);
        if (k < D_TOT) {
            float w  = w_mu[k * KN + n];
            float sp = log1pf(expf(w_sigma[n]));
            bmu[idx] = f2bf(w);
            bsq[idx] = f2bf((w * w + sp) * (1.0f / 400.0f));
        } else {
            bmu[idx] = 0;
            bsq[idx] = 0;
        }
    } else {
        float s = 0.f;
        for (int i = t; i < D_TOT * KN; i += 256) { float w = w_mu[i]; s += w * w; }
        red[t] = s;
        __syncthreads();
        for (int off = 128; off > 0; off >>= 1) {
            if (t < off) red[t] += red[t + off];
            __syncthreads();
        }
        float sum_w2 = red[0];
        if (t < KN) {
            float ws = w_sigma[t];
            spw[t] = log1pf(expf(ws)) * (1.0f / 400.0f);
        }
        if (t == 0) {
            float sws = 0.f;
            for (int kn = 0; kn < KN; ++kn) {
                float ws = w_sigma[kn];
                float sp = log1pf(expf(ws));
                sws += -ws + sp * 100.0f;
            }
            float kl = 0.5f * (-4.605170186f - 1.0f + sws * (1.0f / 32.0f)
                               + sum_w2 * (100.0f / 12800.0f));
            *kl_out = kl;
        }
    }
}

// ---------------- staging helpers ----------------
__device__ __forceinline__ void stage_load(const float* __restrict__ mu_in,
                                           const float* __restrict__ sig_in,
                                           int b, int ho0, int wo0, int i,
                                           float4& vm, float4& vs) {
    int row = i / 80;
    int rem = i - row * 80;
    int col = rem >> 2, c4 = rem & 3;
    int gh = ho0 + row, gw = wo0 + col;
    vm = make_float4(0.f, 0.f, 0.f, 0.f); vs = vm;
    if (gh < H && gw < W) {
        size_t g = (((size_t)b * H + gh) * W + gw) * CIN + c4 * 4;
        vm = *(const float4*)(mu_in + g);
        vs = *(const float4*)(sig_in + g);
    }
}
__device__ __forceinline__ void stage_write(ushort* __restrict__ buf, int i,
                                            float4 vm, float4 vs) {
    int row = i / 80;
    int rem = i - row * 80;
    int col = rem >> 2, c4 = rem & 3;
    int sb = (row * IN_C + col) * CPAD + c4 * 4;
    *(ushort4*)&buf[sb] = pk4(vm);
    *(ushort4*)&buf[TILE_SH + sb] = pk4(vs);
}

// ---------------- per-tile compute (csum -> t12 -> k-loop -> epilogue) ------
// Caller must __syncthreads() after the buffer is fully staged.
__device__ __forceinline__ void process_tile(
        const ushort* __restrict__ bufp, int zpad_rel,
        float* __restrict__ csum, float* __restrict__ t12s,
        const short8* __restrict__ Bmu8, const short8* __restrict__ Bsq8,
        const float* __restrict__ spw,
        int b, int ho0, int wo0,
        float* __restrict__ mu_out, float* __restrict__ sig_out) {
    const int t = threadIdx.x;

    // csum = sum_c mu^2 per input pixel (trace term lives in Bsq)
    if (t < IN_R * IN_C) {
        int sb = t * CPAD;
        float acc = 0.f;
#pragma unroll
        for (int g = 0; g < 4; ++g) {
            ushort4 m4 = *(const ushort4*)&bufp[sb + g * 4];
            float m0 = bf2f(m4.x), m1 = bf2f(m4.y), m2 = bf2f(m4.z), m3 = bf2f(m4.w);
            acc += m0 * m0 + m1 * m1 + m2 * m2 + m3 * m3;
        }
        csum[t] = acc;
    }
    __syncthreads();

    if (t < TH * TW) {
        int r = t >> 4, c = t & 15;
        float s = 0.f;
#pragma unroll
        for (int kh = 0; kh < KK; ++kh)
#pragma unroll
            for (int kw = 0; kw < KK; ++kw)
                s += csum[(r + kh) * IN_C + c + kw];
        t12s[t] = s;
    }
    __syncthreads();

    const int w   = t >> 6;
    const int l   = t & 63;
    const int col = l & 15;
    const int q   = l >> 4;
    const int qh  = q >> 1;
    const int qc  = q & 1;

    const char* lds = (const char*)bufp;
    int base0 = ((2 * w + 0) * IN_C + col) * (CPAD * 2) + qc * 16;
    int base1 = ((2 * w + 1) * IN_C + col) * (CPAD * 2) + qc * 16;
    const int qh48  = qh * 48;
    const int qh768 = qh * 768;
    const int SGOFF = TILE_SH * 2;

    f32x4 accm[2][2], accs[2][2];
    f32x4 z4 = {0.f, 0.f, 0.f, 0.f};
#pragma unroll
    for (int a = 0; a < 2; ++a)
#pragma unroll
        for (int bn = 0; bn < 2; ++bn) { accm[a][bn] = z4; accs[a][bn] = z4; }

    constexpr int F0v[NKSTEP] = {0, 2, 4, 21, 23, 40, 42, 44, 61, 63, 80, 82, 84};
    constexpr int D16[NKSTEP] = {0, 0, 1, 0, 0, 0, 0, 1, 0, 0, 0, 0, 2};

#pragma unroll
    for (int ts = 0; ts < NKSTEP; ++ts) {
        short8 am0, am1, as0, as1;
        if (D16[ts] == 2) {  // last step: odd (kh,kw) position is k>=400 padding
            int a0 = qh ? zpad_rel : (base0 + F0v[ts] * 48);
            int a1 = qh ? zpad_rel : (base1 + F0v[ts] * 48);
            am0 = *(const short8*)(lds + a0);
            am1 = *(const short8*)(lds + a1);
            as0 = *(const short8*)(lds + a0 + (qh ? 0 : SGOFF));
            as1 = *(const short8*)(lds + a1 + (qh ? 0 : SGOFF));
        } else {
            int ex = (D16[ts] ? qh768 : qh48) + F0v[ts] * 48;
            am0 = *(const short8*)(lds + base0 + ex);
            am1 = *(const short8*)(lds + base1 + ex);
            as0 = *(const short8*)(lds + SGOFF + base0 + ex);
            as1 = *(const short8*)(lds + SGOFF + base1 + ex);
        }
        short8 bm0 = Bmu8[(ts * 2 + 0) * 64 + l];
        short8 bm1 = Bmu8[(ts * 2 + 1) * 64 + l];
        short8 bs0 = Bsq8[(ts * 2 + 0) * 64 + l];
        short8 bs1 = Bsq8[(ts * 2 + 1) * 64 + l];

        accm[0][0] = __builtin_amdgcn_mfma_f32_16x16x32_bf16(am0, bm0, accm[0][0], 0, 0, 0);
        accm[0][1] = __builtin_amdgcn_mfma_f32_16x16x32_bf16(am0, bm1, accm[0][1], 0, 0, 0);
        accm[1][0] = __builtin_amdgcn_mfma_f32_16x16x32_bf16(am1, bm0, accm[1][0], 0, 0, 0);
        accm[1][1] = __builtin_amdgcn_mfma_f32_16x16x32_bf16(am1, bm1, accm[1][1], 0, 0, 0);
        accs[0][0] = __builtin_amdgcn_mfma_f32_16x16x32_bf16(as0, bs0, accs[0][0], 0, 0, 0);
        accs[0][1] = __builtin_amdgcn_mfma_f32_16x16x32_bf16(as0, bs1, accs[0][1], 0, 0, 0);
        accs[1][0] = __builtin_amdgcn_mfma_f32_16x16x32_bf16(as1, bs0, accs[1][0], 0, 0, 0);
        accs[1][1] = __builtin_amdgcn_mfma_f32_16x16x32_bf16(as1, bs1, accs[1][1], 0, 0, 0);
    }

    // ---- epilogue (GUARDS RESTORED: grid covers 64x64 > 60x60 outputs) ----
    const float spw0 = spw[col], spw1 = spw[16 + col];
#pragma unroll
    for (int mt = 0; mt < 2; ++mt) {
        int ho = ho0 + 2 * w + mt;
        if (ho >= HO) continue;
#pragma unroll
        for (int reg = 0; reg < 4; ++reg) {
            int wo = wo0 + q * 4 + reg;
            if (wo >= WO) continue;
            float t12v = t12s[(2 * w + mt) * TW + q * 4 + reg];
            size_t basep = (((size_t)b * HO + ho) * WO + wo) * KN;
            mu_out[basep + col]      = accm[mt][0][reg];
            mu_out[basep + 16 + col] = accm[mt][1][reg];
            float s0 = accs[mt][0][reg] + t12v * spw0;
            float s1 = accs[mt][1][reg] + t12v * spw1;
            sig_out[basep + col]      = softplusf(s0);
            sig_out[basep + 16 + col] = softplusf(s1);
        }
    }
}

// ---------------- main: 2 tiles per block, double-buffered ----------------
__global__ __launch_bounds__(256, 3)
void vdp_main(const float* __restrict__ mu_in, const float* __restrict__ sig_in,
              const ushort* __restrict__ bmu_g, const ushort* __restrict__ bsq_g,
              const float* __restrict__ spw,
              float* __restrict__ mu_out, float* __restrict__ sig_out) {
    __shared__ ushort tiles[2 * 2 * TILE_SH + 8];   // two buffers + zero pad
    __shared__ float csum[IN_R * IN_C];
    __shared__ float t12s[TH * TW];

    const int b0  = blockIdx.z;          // 0..15
    const int b1  = blockIdx.z + 16;     // 16..31
    const int ho0 = blockIdx.y * TH;
    const int wo0 = blockIdx.x * TW;
    const int t   = threadIdx.x;

    if (t < 8) tiles[2 * 2 * TILE_SH + t] = 0;   // shared zero pad

    // ---- stage tile0 (batch b0) into buffer 0 ----
    for (int i = t; i < NLOAD; i += 256) {
        float4 vm, vs;
        stage_load(mu_in, sig_in, b0, ho0, wo0, i, vm, vs);
        stage_write(tiles, i, vm, vs);
    }
    __syncthreads();

    // ---- issue tile1 (batch b1) global loads now; results land in regs and
    //      are consumed only after tile0's compute -> HBM latency hidden ----
    float4 pm[4], ps[4];
#pragma unroll
    for (int it = 0; it < 4; ++it) {
        int i = t + 256 * it;
        if (i < NLOAD) stage_load(mu_in, sig_in, b1, ho0, wo0, i, pm[it], ps[it]);
    }

    const short8* Bmu8 = (const short8*)bmu_g;
    const short8* Bsq8 = (const short8*)bsq_g;

    // ---- tile0: compute + store ----
    process_tile(tiles, 2 * BUF_BYTES, csum, t12s, Bmu8, Bsq8, spw,
                 b0, ho0, wo0, mu_out, sig_out);

    // ---- convert + write tile1 into buffer 1 ----
    ushort* buf1 = tiles + 2 * TILE_SH;
#pragma unroll
    for (int it = 0; it < 4; ++it) {
        int i = t + 256 * it;
        if (i < NLOAD) stage_write(buf1, i, pm[it], ps[it]);
    }
    __syncthreads();

    // ---- tile1: compute + store ----
    process_tile(buf1, BUF_BYTES, csum, t12s, Bmu8, Bsq8, spw,
                 b1, ho0, wo0, mu_out, sig_out);
}

extern "C" void kernel_launch(void* const* d_in, const int* in_sizes, int n_in,
                              void* d_out, int out_size, void* d_ws, size_t ws_size,
                              hipStream_t stream) {
    const float* mu_in   = (const float*)d_in[0];
    const float* sig_in  = (const float*)d_in[1];
    const float* w_mu    = (const float*)d_in[2];
    const float* w_sigma = (const float*)d_in[3];

    float* out     = (float*)d_out;
    float* mu_out  = out;
    float* sig_out = out + (size_t)OUT_PLANE;
    float* kl_out  = out + 2 * (size_t)OUT_PLANE;

    ushort* bmu = (ushort*)d_ws;                    // 13312 shorts
    ushort* bsq = bmu + 13312;                      // 13312 shorts
    float*  spw = (float*)(bsq + 13312);            // 32 floats

    prep_all<<<53, 256, 0, stream>>>(w_mu, w_sigma, bmu, bsq, spw, kl_out);
    vdp_main<<<dim3(4, 8, 16), 256, 0, stream>>>(mu_in, sig_in, bmu, bsq, spw,
                                                 mu_out, sig_out);
}